// Round 7
// baseline (449.477 us; speedup 1.0000x reference)
//
#include <hip/hip_runtime.h>

#define K_CLUSTERS 512
#define FDIM 64
#define RPB 512      // rows per block; grid = N/RPB = 256 (1 block/CU, LDS-bound)
#define RT 8         // rows per wave-tile
#define NTILES 4     // tiles per wave: RPB / (16 waves * RT)
#define WSTRIDE 17   // vf4 per LDS W row (16 + 1 pad -> bank-quad = (c+f4)%8)

typedef float vf4 __attribute__((ext_vector_type(4)));

// Transpose W [F=64][K=512] -> Wt [K][F] (for epilogue gather), wsq[k].
// UNCHANGED (absmax 0.0 proven).
__global__ __launch_bounds__(64) void vq_prep(const float* __restrict__ W,
                                              float* __restrict__ Wt,
                                              float* __restrict__ wsq) {
    int k = blockIdx.x;
    int f = threadIdx.x;
    float w = W[f * K_CLUSTERS + k];
    Wt[k * FDIM + f] = w;
    float s = w * w;
#pragma unroll
    for (int off = 32; off > 0; off >>= 1) s += __shfl_xor(s, off, 64);
    if (f == 0) wsq[k] = s;
}

// Fused argmin + zq + diff + one-hot.
// Round-7: single-pass CPL=8 x RT=8 (acc[8][8]=64 regs, affordable under the
// waves_per_eu(4,4) VGPR cap of 128). Round 6 (~180 us) matched the
// SERIALIZED pipe sum (VALU 63 + LDS 41 + VMEM 55 + stores) -- 4 waves/SIMD
// can't hide load latency. This round: zb broadcast loads halved (4096/CPL
// per wave), one f4 iteration issues 16 independent loads (8 LDS + 8 VMEM)
// ahead of 256 fmafs so latency hides within a wave. q/wsq loads deferred to
// distance time to keep the f4-loop live set ~118 regs.
// All arithmetic chains bit-identical to the proven kernels (absmax 0.0):
// per-(r,c) dot = one accumulator over ascending f; fmaf(-2,dot,s)+wsq;
// 8-lane sumz chains + shfl_xor tree (proven r3/5/6); update order j
// ascending == c ascending, strict < + tie-index == np.argmin first-index;
// contract-off epilogue; butterfly/epilogue/one-hot verbatim from round 6.
__global__ __launch_bounds__(1024)
__attribute__((amdgpu_waves_per_eu(4, 4)))
void vq_fused(const float* __restrict__ z,
              const float* __restrict__ W,
              const float* __restrict__ Wt,
              const float* __restrict__ wsq,
              float* __restrict__ out_zq,
              float* __restrict__ out_idx,
              float* __restrict__ enc,
              float* __restrict__ out_diff) {
    __shared__ vf4 sW4[K_CLUSTERS * WSTRIDE];   // 136 KB, the only LDS

    const int tid = threadIdx.x;
    // wave index as a compiler-provable SGPR: z-tile base stays uniform.
    const int w = __builtin_amdgcn_readfirstlane(tid) >> 6;
    const int l = tid & 63;

    // ---- Stage W into LDS (coalesced vf4 reads, strided scalar writes) ----
    {
        float* sWf = (float*)sW4;
        const vf4* Wg4 = (const vf4*)W;
#pragma unroll
        for (int it = 0; it < 8; it++) {
            int u4 = it * 1024 + tid;       // vf4 index over W (8192 total)
            vf4 v = Wg4[u4];
            int u = u4 << 2;                // float index; 4 elems same f, c0..c0+3
            int f = u >> 9;
            int c0 = u & 511;
            int f4 = f >> 2, m = f & 3;
#pragma unroll
            for (int e = 0; e < 4; e++) {
                int c = c0 + e;
                sWf[c * (4 * WSTRIDE) + (f4 << 2) + m] = v[e];
            }
        }
    }
    __syncthreads();  // the only barrier in the kernel

    const int rowW = blockIdx.x * RPB + w * (RT * NTILES);
    const vf4* zg4 = (const vf4*)z;
    // lane l owns clusters c = j*64 + l, j = 0..7 (single pass)
    const vf4* wB = sW4 + l * WSTRIDE;
    const vf4* wB4 = wB + 256 * WSTRIDE;    // second base: keeps ds imm offsets small

#pragma unroll 1
    for (int t = 0; t < NTILES; t++) {
        const int row0 = rowW + t * RT;     // wave-uniform (SGPR)

        // ---- sumz: 8 lanes per row, one exact accumulator chain per lane ----
        // (proven bit-exact rounds 3/5/6)
        float srow;
        {
            const float* zr = z + (size_t)(row0 + (l >> 3)) * FDIM;
            const int j = l & 7;
            float rj;
            {
#pragma clang fp contract(off)
                rj = zr[j] * zr[j];
#pragma unroll
                for (int b = 8; b < 64; b += 8) rj += zr[b + j] * zr[b + j];
            }
            float s01 = rj + __shfl_xor(rj, 1, 64);
            float s03 = s01 + __shfl_xor(s01, 2, 64);
            srow = s03 + __shfl_xor(s03, 4, 64);
        }
        float sA[RT];
#pragma unroll
        for (int r = 0; r < RT; r++) sA[r] = __shfl(srow, r << 3, 64);

        const vf4* zt = zg4 + (size_t)row0 * 16;  // uniform z tile base (SGPR)

        float acc[RT][8];
#pragma unroll
        for (int r = 0; r < RT; r++)
#pragma unroll
            for (int j = 0; j < 8; j++) acc[r][j] = 0.0f;

        // ---- single pass: 8 wv + 8 zb loads per f4, then 256 fmafs ----
#pragma unroll 1
        for (int f4 = 0; f4 < 16; f4++) {
            vf4 wv0 = wB[f4];                       // j stride = 64*WSTRIDE vf4
            vf4 wv1 = wB[64 * WSTRIDE + f4];
            vf4 wv2 = wB[128 * WSTRIDE + f4];
            vf4 wv3 = wB[192 * WSTRIDE + f4];
            vf4 wv4 = wB4[f4];
            vf4 wv5 = wB4[64 * WSTRIDE + f4];
            vf4 wv6 = wB4[128 * WSTRIDE + f4];
            vf4 wv7 = wB4[192 * WSTRIDE + f4];
#pragma unroll
            for (int r = 0; r < RT; r++) {
                vf4 zb = zt[(r << 4) + f4];         // uniform 16B broadcast
                float a0 = acc[r][0], a1 = acc[r][1], a2 = acc[r][2], a3 = acc[r][3];
                float a4 = acc[r][4], a5 = acc[r][5], a6 = acc[r][6], a7 = acc[r][7];
                a0 = fmaf(zb.x, wv0.x, a0); a1 = fmaf(zb.x, wv1.x, a1);
                a2 = fmaf(zb.x, wv2.x, a2); a3 = fmaf(zb.x, wv3.x, a3);
                a4 = fmaf(zb.x, wv4.x, a4); a5 = fmaf(zb.x, wv5.x, a5);
                a6 = fmaf(zb.x, wv6.x, a6); a7 = fmaf(zb.x, wv7.x, a7);
                a0 = fmaf(zb.y, wv0.y, a0); a1 = fmaf(zb.y, wv1.y, a1);
                a2 = fmaf(zb.y, wv2.y, a2); a3 = fmaf(zb.y, wv3.y, a3);
                a4 = fmaf(zb.y, wv4.y, a4); a5 = fmaf(zb.y, wv5.y, a5);
                a6 = fmaf(zb.y, wv6.y, a6); a7 = fmaf(zb.y, wv7.y, a7);
                a0 = fmaf(zb.z, wv0.z, a0); a1 = fmaf(zb.z, wv1.z, a1);
                a2 = fmaf(zb.z, wv2.z, a2); a3 = fmaf(zb.z, wv3.z, a3);
                a4 = fmaf(zb.z, wv4.z, a4); a5 = fmaf(zb.z, wv5.z, a5);
                a6 = fmaf(zb.z, wv6.z, a6); a7 = fmaf(zb.z, wv7.z, a7);
                a0 = fmaf(zb.w, wv0.w, a0); a1 = fmaf(zb.w, wv1.w, a1);
                a2 = fmaf(zb.w, wv2.w, a2); a3 = fmaf(zb.w, wv3.w, a3);
                a4 = fmaf(zb.w, wv4.w, a4); a5 = fmaf(zb.w, wv5.w, a5);
                a6 = fmaf(zb.w, wv6.w, a6); a7 = fmaf(zb.w, wv7.w, a7);
                acc[r][0] = a0; acc[r][1] = a1; acc[r][2] = a2; acc[r][3] = a3;
                acc[r][4] = a4; acc[r][5] = a5; acc[r][6] = a6; acc[r][7] = a7;
            }
        }

        // ---- distances + thread-local lex-min (j ascending == c ascending) ----
        float bd[RT];
        int bk[RT];
#pragma unroll
        for (int r = 0; r < RT; r++) { bd[r] = INFINITY; bk[r] = 0; }
#pragma unroll
        for (int j = 0; j < 8; j++) {
            const int c = (j << 6) + l;
            const float q = wsq[c];
#pragma unroll
            for (int r = 0; r < RT; r++) {
                float d = fmaf(-2.0f, acc[r][j], sA[r]) + q;
                if (d < bd[r] || (d == bd[r] && c < bk[r])) { bd[r] = d; bk[r] = c; }
            }
        }

        // ---- 64-lane butterfly lex-min; 8 independent row-chains interleave ----
#pragma unroll
        for (int off = 1; off < 64; off <<= 1) {
#pragma unroll
            for (int r = 0; r < RT; r++) {
                float od = __shfl_xor(bd[r], off, 64);
                int ok = __shfl_xor(bk[r], off, 64);
                if (od < bd[r] || (od == bd[r] && ok < bk[r])) { bd[r] = od; bk[r] = ok; }
            }
        }
        // all lanes now hold the final (bd,bk) for all 8 rows

        if (l == 0) {
#pragma unroll
            for (int r = 0; r < RT; r++) out_idx[row0 + r] = (float)bk[r];
        }

        // ---- zq & diff (z re-read from L1/L2, w gather from Wt; bit-exact) ----
#pragma unroll
        for (int h = 0; h < 2; h++) {
            const int rsel = l >> 4;              // 0..3 within half
            int kk = bk[4 * h + 0];
            if (rsel == 1) kk = bk[4 * h + 1];
            if (rsel == 2) kk = bk[4 * h + 2];
            if (rsel == 3) kk = bk[4 * h + 3];
            vf4 zvv = zt[(h << 6) + l];           // == z[row0 + 4h + rsel][chunk]
            vf4 wvv = ((const vf4*)Wt)[((size_t)kk << 4) + (l & 15)];
            vf4 zq, df;
            {
#pragma clang fp contract(off)
                vf4 d1 = wvv - zvv;
                zq = zvv + d1;
                df = d1 * d1;
            }
            ((vf4*)out_zq)[(size_t)row0 * 16 + (h << 6) + l] = zq;
            ((vf4*)out_diff)[(size_t)row0 * 16 + (h << 6) + l] = df;
        }

        // ---- one-hot: coalesced plain stores, 16 x 1KB per wave-tile ----
        {
            vf4* enc4 = (vf4*)enc + (size_t)row0 * 128;
#pragma unroll
            for (int jj = 0; jj < 16; jj++) {
                const int row = jj >> 1;     // compile-time per unrolled jj
                int kk = bk[row];
                int c = kk - ((l + ((jj & 1) << 6)) << 2);
                vf4 v;
                v.x = (c == 0) ? 1.0f : 0.0f;
                v.y = (c == 1) ? 1.0f : 0.0f;
                v.z = (c == 2) ? 1.0f : 0.0f;
                v.w = (c == 3) ? 1.0f : 0.0f;
                enc4[(jj << 6) + l] = v;
            }
        }
    }
}

extern "C" void kernel_launch(void* const* d_in, const int* in_sizes, int n_in,
                              void* d_out, int out_size, void* d_ws, size_t ws_size,
                              hipStream_t stream) {
    const float* z = (const float*)d_in[0];
    const float* W = (const float*)d_in[1];
    int N = in_sizes[0] / FDIM;  // 131072

    float* out = (float*)d_out;
    float* out_zq = out;
    float* out_idx = out_zq + (size_t)N * FDIM;
    float* enc = out_idx + N;
    float* out_diff = enc + (size_t)N * K_CLUSTERS;

    float* Wt = (float*)d_ws;
    float* wsq = Wt + K_CLUSTERS * FDIM;

    vq_prep<<<K_CLUSTERS, 64, 0, stream>>>(W, Wt, wsq);
    vq_fused<<<N / RPB, 1024, 0, stream>>>(z, W, Wt, wsq, out_zq, out_idx, enc, out_diff);
}